// Round 12
// baseline (92.837 us; speedup 1.0000x reference)
//
#include <hip/hip_runtime.h>

#define NHEADS 16
#define NW 8
#define SEQ 1024
#define BATCH 8
#define EMB 128

typedef _Float16 half2_t __attribute__((ext_vector_type(2)));
typedef _Float16 half4_t __attribute__((ext_vector_type(4)));
typedef _Float16 half8_t __attribute__((ext_vector_type(8)));
typedef float    f32x4   __attribute__((ext_vector_type(4)));

__device__ __forceinline__ half2_t pkrtz(float a, float b) {
    return __builtin_bit_cast(half2_t, __builtin_amdgcn_cvt_pkrtz(a, b));
}

// qattn smem layout in halves:
//   kvh  [1024 keys][8 dims]            @ 0      (16 KB, row-major)
//   kvhT [8 dims][stride 1040]          @ 8192   (16.25 KB, transposed, padded)
//   ones [8]                            @ 16512
//   zero [8]                            @ 16520
#define KVT       8192
#define KVT_STR   1040
#define ONES_OFF  16512
#define ZERO_OFF  16520
#define SMEM_H    16544        // + pad for last-iteration prefetch overrun

// quantum_heads closed form for one (b,s,head) row (fp32 input):
// c[w] = cos(x[w] + theta[w]); z[0] = c1..c7; z[w>=1] = c0..cw
__device__ __forceinline__ void qrow(const float* __restrict__ xp,
                                     const float* __restrict__ th, float* z) {
    float4 a = *reinterpret_cast<const float4*>(xp);
    float4 b = *reinterpret_cast<const float4*>(xp + 4);
    float c0 = __cosf(a.x + th[0]);
    float c1 = __cosf(a.y + th[1]);
    float c2 = __cosf(a.z + th[2]);
    float c3 = __cosf(a.w + th[3]);
    float c4 = __cosf(b.x + th[4]);
    float c5 = __cosf(b.y + th[5]);
    float c6 = __cosf(b.z + th[6]);
    float c7 = __cosf(b.w + th[7]);
    float u = c1 * c2;
    u *= c3; u *= c4; u *= c5; u *= c6; u *= c7;
    z[0] = u;
    z[1] = c0 * c1;
    z[2] = z[1] * c2;
    z[3] = z[2] * c3;
    z[4] = z[3] * c4;
    z[5] = z[4] * c5;
    z[6] = z[5] * c6;
    z[7] = z[6] * c7;
}

// MFMA attention (UNCHANGED from R11 — hardware-verified).
// grid = 128 bh * 8 qsplits = 1024 blocks, 256 threads.
__global__ __launch_bounds__(256, 4) void qattn_mfma(
    const float* __restrict__ x,
    const float* __restrict__ theta,
    __fp16* __restrict__ P)        // [B*S][128] f16, normalized attn@h
{
    __shared__ __align__(16) _Float16 smem[SMEM_H];
    const int t   = threadIdx.x;
    const int bid = blockIdx.x;
    const int qs  = bid & 7;                // query octant (128 q)
    const int bh  = bid >> 3;               // 0..127
    const int b   = bh >> 4, h = bh & 15;

    float th[8];
#pragma unroll
    for (int w = 0; w < 8; ++w) th[w] = theta[w];   // wave-uniform -> s_loads

    // ---- stage all 1024 keys: row-major f16 + transposed copy ----
#pragma unroll
    for (int i = 0; i < 4; ++i) {
        const int kl = t + 256 * i;
        float z[8];
        qrow(x + ((size_t)(b * SEQ + kl) * EMB + h * NW), th, z);
        half8_t hv;
#pragma unroll
        for (int d = 0; d < 8; ++d) hv[d] = (_Float16)z[d];
        *reinterpret_cast<half8_t*>(&smem[kl * 8]) = hv;
#pragma unroll
        for (int d = 0; d < 8; ++d) smem[KVT + d * KVT_STR + kl] = hv[d];
    }
    if (t < 8)              smem[ONES_OFF + t]     = (_Float16)1.0f;
    else if (t < 16)        smem[ZERO_OFF + t - 8] = (_Float16)0.0f;
    __syncthreads();

    const int lane = t & 63;
    const int wv   = t >> 6;
    const int q16  = lane & 15;
    const int qd   = lane >> 4;             // quad 0..3
    const int qbase = qs * 128 + wv * 32;

    // ---- Q fragments (B operand): B[k=dim][n=q], quads!=0 read zeros ----
    const _Float16 QSh = (_Float16)0.51012924f;   // (1/sqrt(8))*log2(e)
    half8_t qfrag[2];
#pragma unroll
    for (int qi = 0; qi < 2; ++qi) {
        const _Float16* qp = (qd == 0)
            ? &smem[(qbase + qi * 16 + q16) * 8] : &smem[ZERO_OFF];
        half8_t qv = *reinterpret_cast<const half8_t*>(qp);
#pragma unroll
        for (int j = 0; j < 8; ++j) qv[j] = qv[j] * QSh;
        qfrag[qi] = qv;
    }

    // ---- loop-invariant pointers / lane constants ----
    const _Float16* ka = (qd == 0) ? &smem[q16 * 8]        : &smem[ZERO_OFF];
    const _Float16* kb = (qd == 0) ? &smem[(16 + q16) * 8] : &smem[ZERO_OFF];
    const int kstep = (qd == 0) ? 256 : 0;          // 32 keys * 8 halves
    const _Float16* vp; int vstep;
    if (q16 < 8)       { vp = &smem[KVT + q16 * KVT_STR + qd * 8]; vstep = 32; }
    else if (q16 == 8) { vp = &smem[ONES_OFF]; vstep = 0; }
    else               { vp = &smem[ZERO_OFF]; vstep = 0; }

    const bool oddq = (qd & 1);                         // source-side publication
    const bool hiC  = (qd >= 2);                        // dest-side swap
    const int  iA   = (q16 + (qd & 1) * 32 + (qd >> 1) * 16) * 4;
    const int  iB   = iA ^ 64;
    const int  lidx = (32 + q16) * 4;                   // lane holding dim-8 row (l)

    f32x4 oacc[2] = {{0.f, 0.f, 0.f, 0.f}, {0.f, 0.f, 0.f, 0.f}};
    const f32x4 zc = {0.f, 0.f, 0.f, 0.f};

    half8_t kA = *reinterpret_cast<const half8_t*>(ka);
    half8_t kB = *reinterpret_cast<const half8_t*>(kb);
    half8_t vA = *reinterpret_cast<const half8_t*>(vp);

    for (int kt = 0; kt < 32; ++kt) {
        ka += kstep; kb += kstep; vp += vstep;
        half8_t nkA = *reinterpret_cast<const half8_t*>(ka);   // prefetch (pad-safe)
        half8_t nkB = *reinterpret_cast<const half8_t*>(kb);
        half8_t nvA = *reinterpret_cast<const half8_t*>(vp);

#pragma unroll
        for (int qi = 0; qi < 2; ++qi) {
            // S^T tiles: C[row=key=qd*4+reg][col=q=lane&15]
            f32x4 c0 = __builtin_amdgcn_mfma_f32_16x16x32_f16(kA, qfrag[qi], zc, 0, 0, 0);
            f32x4 c1 = __builtin_amdgcn_mfma_f32_16x16x32_f16(kB, qfrag[qi], zc, 0, 0, 0);
            // p0/p1 = local keys 4qd+{0,1}/{2,3}; p2/p3 = keys 16+4qd+{0,1}/{2,3}
            half2_t p0 = pkrtz(__builtin_amdgcn_exp2f(c0[0]), __builtin_amdgcn_exp2f(c0[1]));
            half2_t p1 = pkrtz(__builtin_amdgcn_exp2f(c0[2]), __builtin_amdgcn_exp2f(c0[3]));
            half2_t p2 = pkrtz(__builtin_amdgcn_exp2f(c1[0]), __builtin_amdgcn_exp2f(c1[1]));
            half2_t p3 = pkrtz(__builtin_amdgcn_exp2f(c1[2]), __builtin_amdgcn_exp2f(c1[3]));
            union { half2_t h; int i; } u0, u1, u2, u3;
            u0.h = p0; u1.h = p1; u2.h = p2; u3.h = p3;
            // publication: quads {0,2} -> (p0,p1,p2,p3); quads {1,3} -> (p2,p3,p0,p1)
            const int a0 = oddq ? u2.i : u0.i;
            const int a1 = oddq ? u3.i : u1.i;
            const int a2 = oddq ? u0.i : u2.i;
            const int a3 = oddq ? u1.i : u3.i;
            const int r0 = __builtin_amdgcn_ds_bpermute(iA, a0);
            const int r1 = __builtin_amdgcn_ds_bpermute(iA, a1);
            const int r2 = __builtin_amdgcn_ds_bpermute(iB, a2);
            const int r3 = __builtin_amdgcn_ds_bpermute(iB, a3);
            // assemble B-operand P^T frag: element j = P[key=qd*8+j][q=lane&15]
            union { int i[4]; half8_t h; } bf;
            bf.i[0] = hiC ? r2 : r0;
            bf.i[1] = hiC ? r3 : r1;
            bf.i[2] = hiC ? r0 : r2;
            bf.i[3] = hiC ? r1 : r3;
            // O^T += Vx^T . P^T  (ones col -> row-sum l in dim 8)
            oacc[qi] = __builtin_amdgcn_mfma_f32_16x16x32_f16(vA, bf.h, oacc[qi], 0, 0, 0);
        }
        kA = nkA; kB = nkB; vA = nvA;
    }

    // ---- epilogue: normalize by l (row 8 = quad2 reg0), write P f16 ----
#pragma unroll
    for (int qi = 0; qi < 2; ++qi) {
        f32x4 c = oacc[qi];
        const float lsum = __int_as_float(
            __builtin_amdgcn_ds_bpermute(lidx, __float_as_int(c[0])));
        const float inv = 1.0f / lsum;
        if (qd < 2) {                       // quads 0,1 hold dims 0-7
            half2_t u0 = pkrtz(c[0] * inv, c[1] * inv);
            half2_t u1 = pkrtz(c[2] * inv, c[3] * inv);
            half4_t o4; o4[0] = u0[0]; o4[1] = u0[1]; o4[2] = u1[0]; o4[3] = u1[1];
            const int row = b * SEQ + qbase + qi * 16 + q16;
            *reinterpret_cast<half4_t*>(
                reinterpret_cast<_Float16*>(P) + (size_t)row * EMB + h * NW + qd * 4) = o4;
        }
    }
}

// W (f32 [128][128]) -> Wh (f16), 16384 elems. 16 blocks x 256, 4/thread.
__global__ __launch_bounds__(256) void wcast(
    const float* __restrict__ W, _Float16* __restrict__ Wh)
{
    const int g = (blockIdx.x * 256 + threadIdx.x) * 4;
    float4 v = *reinterpret_cast<const float4*>(W + g);
    half4_t h;
    h[0] = (_Float16)v.x; h[1] = (_Float16)v.y;
    h[2] = (_Float16)v.z; h[3] = (_Float16)v.w;
    *reinterpret_cast<half4_t*>(Wh + g) = h;
}

// MFMA projection: out[row][e] = sum_f P[row][f]*Wh[e][f] + bias[e].
// No LDS, no barriers; A and B frags straight from global (L2-hot).
// grid = 512 blocks x 256 thr; block = 16 rows, wave wv = col quarter wv*32.
// Frag layouts hardware-verified in R11: A m=lane&15,k=quad*8+j;
// B n=lane&15,k=quad*8+j; C col=lane&15, row=quad*4+reg.
__global__ __launch_bounds__(256) void proj_mfma(
    const __fp16* __restrict__ Pv,
    const _Float16* __restrict__ Wh,
    const float* __restrict__ bias,
    float* __restrict__ out)
{
    const _Float16* P = reinterpret_cast<const _Float16*>(Pv);
    const int t    = threadIdx.x;
    const int lane = t & 63;
    const int wv   = t >> 6;
    const int n16  = lane & 15;
    const int qd   = lane >> 4;
    const int row0 = blockIdx.x * 16;
    const int col0 = wv * 32;

    // A fragments: P rows, k = kb*32 + qd*8 + j (contiguous half8)
    half8_t a[4];
#pragma unroll
    for (int kb = 0; kb < 4; ++kb)
        a[kb] = *reinterpret_cast<const half8_t*>(
            P + (size_t)(row0 + n16) * EMB + kb * 32 + qd * 8);

    const f32x4 zc = {0.f, 0.f, 0.f, 0.f};
#pragma unroll
    for (int et = 0; et < 2; ++et) {
        const int e = col0 + et * 16 + n16;
        f32x4 acc = zc;
#pragma unroll
        for (int kb = 0; kb < 4; ++kb) {
            half8_t bfr = *reinterpret_cast<const half8_t*>(
                Wh + (size_t)e * EMB + kb * 32 + qd * 8);
            acc = __builtin_amdgcn_mfma_f32_16x16x32_f16(a[kb], bfr, acc, 0, 0, 0);
        }
        const float bv = bias[e];
#pragma unroll
        for (int r = 0; r < 4; ++r)
            out[(size_t)(row0 + qd * 4 + r) * EMB + e] = acc[r] + bv;
    }
}

extern "C" void kernel_launch(void* const* d_in, const int* in_sizes, int n_in,
                              void* d_out, int out_size, void* d_ws, size_t ws_size,
                              hipStream_t stream)
{
    const float* x     = (const float*)d_in[0];
    const float* theta = (const float*)d_in[1];
    const float* W     = (const float*)d_in[2];
    const float* bias  = (const float*)d_in[3];
    float* out = (float*)d_out;

    __fp16*   Pw = (__fp16*)d_ws;                              // 2 MB
    _Float16* Wh = (_Float16*)((char*)d_ws + (size_t)BATCH * SEQ * EMB * 2);

    wcast<<<16, 256, 0, stream>>>(W, Wh);
    qattn_mfma<<<128 * 8, 256, 0, stream>>>(x, theta, Pw);
    proj_mfma<<<BATCH * SEQ / 16, 256, 0, stream>>>(Pw, Wh, bias, out);
}